// Round 8
// baseline (254.911 us; speedup 1.0000x reference)
//
#include <hip/hip_runtime.h>

// NoMCOutModel round 22: r21 + depth-1 manual software pipeline in the R
// loop + it-invariant J-tile/bias hoisting.
// r21 post-mortem: balance confirmed (-16us, spill gone), but VALU
// busy-cycles fell 100->71us: '#pragma unroll 1' killed cross-group load
// pipelining, so each R group eats ~250cy L2 latency at its head (L1 is
// thrashed: 16 waves x 18KB tiles = 288KB >> 32KB). 4 waves/SIMD TLP can't
// cover it alone.
// This round: explicit depth-1 rotation -- named regs rc0..rc3/rb0..rb3
// hold group g's tiles; while computing g, issue loads for g+1 into
// n0..n3/a0..a3 (guard g!=3). No arrays -> no dynamic-index scratch; ~100
// VGPR peak < 128 cap. J tiles + J biases are it-INVARIANT (address = f(w))
// -> loaded once before the it loop. J-finalize moved right after barrier A
// (overlaps R compute; ph written pre-A, xj consumed post-B).
// Scan/m_in/prep/epilogue: identical to r21.

namespace {

constexpr int B_ = 256, T_ = 256, M_ = 8, AUX_ = 32, H_ = 64;
constexpr int NTILE = 288;               // (64*64 + 8*64)/16 logit col-tiles
constexpr float LOG2E = 1.4426950408889634f;

typedef __fp16 f16x2 __attribute__((ext_vector_type(2)));
typedef __fp16 f16x8 __attribute__((ext_vector_type(8)));
typedef float  f32x4 __attribute__((ext_vector_type(4)));
typedef int    i32x4 __attribute__((ext_vector_type(4)));

union V8 { f16x8 v; f16x2 p[4]; i32x4 i; };

#if __has_builtin(__builtin_amdgcn_exp2f)
#define EXP2(x) __builtin_amdgcn_exp2f(x)
#else
#define EXP2(x) exp2f(x)
#endif

#define MFMA16(A, Bv, C) __builtin_amdgcn_mfma_f32_16x16x32_f16((A), (Bv), (C), 0, 0, 0)

__device__ __forceinline__ float dot2(f16x2 a, f16x2 b, float c) {
    return __builtin_amdgcn_fdot2(a, b, c, false);
}

template <int CTRL>
__device__ __forceinline__ float dpp_add(float v) {
    int t = __builtin_amdgcn_update_dpp(0, __builtin_bit_cast(int, v),
                                        CTRL, 0xf, 0xf, true);
    return v + __builtin_bit_cast(float, t);
}
__device__ __forceinline__ float sum16_all(float v) {
    v = dpp_add<0xB1>(v);   // quad_perm [1,0,3,2]
    v = dpp_add<0x4E>(v);   // quad_perm [2,3,0,1]
    v = dpp_add<0x141>(v);  // row_half_mirror
    v = dpp_add<0x140>(v);  // row_mirror
    return v;
}
__device__ __forceinline__ float sum64_uni(float v) {
    v = dpp_add<0x111>(v); v = dpp_add<0x112>(v); v = dpp_add<0x114>(v);
    v = dpp_add<0x118>(v); v = dpp_add<0x142>(v); v = dpp_add<0x143>(v);
    return __builtin_bit_cast(float,
        __builtin_amdgcn_readlane(__builtin_bit_cast(int, v), 63));
}

// RNE pair-pack: every lane ends with (f16(chat[2P]), f16(chat[2P+1])) where
// P = lane>>1. Own value is converted RNE ((__fp16) cast = v_cvt_f16_f32),
// then quad_perm DPP broadcasts the even/odd pair members to both lanes.
__device__ __forceinline__ int pack_pair_rne(float v) {
    const int hv = (int)__builtin_bit_cast(unsigned short, (__fp16)v);
    const int ev = __builtin_amdgcn_update_dpp(0, hv, 0xA0, 0xf, 0xf, true); // [0,0,2,2]
    const int ov = __builtin_amdgcn_update_dpp(0, hv, 0xF5, 0xf, 0xf, true); // [1,1,3,3]
    return ev | (ov << 16);
}

#define LDS_FENCE() __asm__ volatile("s_waitcnt lgkmcnt(0)" ::: "memory")

// ---------------- prep: W -> f16 MFMA B-frag layout in ws ----------------
// ws[gt*1024 + lane*16] : f16x8 frag, B[k = (lane>>4)*8 + j][n = gt*16+(lane&15)]
// ws + 288*1024 : float bias[4608] (log2e-scaled)
__global__ __launch_bounds__(64)
void nomc_prep(const float* __restrict__ Wj, const float* __restrict__ bj,
               const float* __restrict__ Wr, const float* __restrict__ br,
               void* __restrict__ ws)
{
    const int gt = blockIdx.x;           // 0..287
    const int l = threadIdx.x, q = l >> 4, l15 = l & 15;
    const float* src; const float* bsrc; int stride;
    if (gt < 256) { const int n = gt * 16 + l15;        src = Wr + n; bsrc = br + n; stride = 4096; }
    else          { const int n = (gt - 256) * 16 + l15; src = Wj + n; bsrc = bj + n; stride = 512; }
    V8 v;
#pragma unroll
    for (int j = 0; j < 4; ++j) {
        const float f0 = src[(q * 8 + 2 * j)     * stride] * LOG2E;
        const float f1 = src[(q * 8 + 2 * j + 1) * stride] * LOG2E;
        v.p[j] = __builtin_amdgcn_cvt_pkrtz(f0, f1);
    }
    *(i32x4*)((char*)ws + (size_t)gt * 1024 + l * 16) = v.i;
    if (l < 16)
        ((float*)((char*)ws + NTILE * 1024))[gt * 16 + l] = bsrc[0] * LOG2E;
}

// one R tile: MFMA -> exp2 -> swizzled RT stores -> rowsum accumulate
#define R_TILE(BF, BV, TT)                                                   \
    do {                                                                     \
        f32x4 acc = {(BV), (BV), (BV), (BV)};                                \
        acc = MFMA16(af.v, (BF).v, acc);                                     \
        const float e0 = EXP2(acc[0]), e1 = EXP2(acc[1]);                    \
        const float e2 = EXP2(acc[2]), e3 = EXP2(acc[3]);                    \
        const int kk = ((TT) << 4) + l15;                                    \
        RT[q * 4 + 0][hb][kk][p] = (__fp16)e0;                               \
        RT[q * 4 + 1][hb][kk][p] = (__fp16)e1;                               \
        RT[q * 4 + 2][hb][kk][p] = (__fp16)e2;                               \
        RT[q * 4 + 3][hb][kk][p] = (__fp16)e3;                               \
        es0 += e0; es1 += e1; es2 += e2; es3 += e3;                          \
    } while (0)

// ---------------- main ----------------
__global__ __launch_bounds__(1024, 4)
void nomc_main(const float* __restrict__ x_m, const float* __restrict__ x_a,
               const float* __restrict__ Wo, const float* __restrict__ bo,
               const float* __restrict__ Wfc, const float* __restrict__ bfc,
               const void* __restrict__ ws, float* __restrict__ out)
{
    const int b = blockIdx.x, tid = threadIdx.x;
    const int w = tid >> 6, l = tid & 63, q = l >> 4, l15 = l & 15;

    __shared__ __align__(16) __fp16 RT[16][8][64][8];   // 131072 B  RT[t][h>>3][k][(h&7)^((t>>2)<<1)]=e
    __shared__ __align__(16) __fp16 JT[16][64][8];      //  16384 B  JT[t][k][m^((t>>2)<<1)]=e_j
    __shared__ float sinv[16][64];                      //   4096 B  1/rowsum(R)
    __shared__ __align__(16) __fp16 xj[16][8];          //    256 B  [t][m^((t>>2)<<1)]=xm/s_j
    __shared__ __align__(16) __fp16 minL[16][64];       //   2048 B  m_in[t][k]
    __shared__ float xm_lds[T_][M_];                    //   8192 B
    __shared__ float cfin_lds[H_];                      //    256 B
    __shared__ float ph[16][16];                        //   1024 B  J half-rowsums [wave][t]
    // total 163328 <= 163840

    {   // stage x_m once
        const float* xmb = x_m + (size_t)b * T_ * M_;
        for (int i = tid; i < T_ * M_; i += 1024) (&xm_lds[0][0])[i] = xmb[i];
    }
    __syncthreads();

    // Balanced produce: wave w owns R groups {4w..4w+3} (16 tiles) + half of
    // J group 64+(w>>1): tiles tt in {0,1} for even w, {2,3} for odd w.
    const char* wsb = (const char*)ws;
    const float* wbias = (const float*)(wsb + NTILE * 1024);
    const int a_sh = w >> 1;                 // shared J group -> m = a_sh
    const int tb = (w & 1) ? 2 : 0;          // J tile base

    const int sx = q << 1;               // store-side bank swizzle (= (t>>2)<<1)

    // ---- it-invariant J tiles + biases (addresses = f(w) only) ----
    V8 tj0, tj1; float bj0, bj1;
    {
        const int gtj = (64 + a_sh) * 4 + tb;
        tj0.i = *(const i32x4*)(wsb + (size_t)(gtj + 0) * 1024 + l * 16);
        tj1.i = *(const i32x4*)(wsb + (size_t)(gtj + 1) * 1024 + l * 16);
        bj0 = wbias[(gtj + 0) * 16 + l15];
        bj1 = wbias[(gtj + 1) * 16 + l15];
    }

    float c0 = 0.f, c1 = 0.f, c2 = 0.f, c3 = 0.f;   // c[kt*16 + l15], q-replicated

    for (int it = 0; it < 16; ++it) {
        // ================= produce: 16 timesteps of exp(logits) =================
        V8 af;
        {   // A-frag: row = l15 -> t = it*16+l15; k = q*8+j
            const float* xa = x_a + ((size_t)b * T_ + it * 16 + l15) * AUX_ + q * 8;
            const f32x4 x0 = *(const f32x4*)xa;
            const f32x4 x1 = *(const f32x4*)(xa + 4);
            af.p[0] = __builtin_amdgcn_cvt_pkrtz(x0.x, x0.y);
            af.p[1] = __builtin_amdgcn_cvt_pkrtz(x0.z, x0.w);
            af.p[2] = __builtin_amdgcn_cvt_pkrtz(x1.x, x1.y);
            af.p[3] = __builtin_amdgcn_cvt_pkrtz(x1.z, x1.w);
        }

        // ---- preload R group 0 (in flight during J half) ----
        V8 rc0, rc1, rc2, rc3; float rb0, rb1, rb2, rb3;
        {
            const int gt0 = (w * 4) * 4;
            rc0.i = *(const i32x4*)(wsb + (size_t)(gt0 + 0) * 1024 + l * 16);
            rc1.i = *(const i32x4*)(wsb + (size_t)(gt0 + 1) * 1024 + l * 16);
            rc2.i = *(const i32x4*)(wsb + (size_t)(gt0 + 2) * 1024 + l * 16);
            rc3.i = *(const i32x4*)(wsb + (size_t)(gt0 + 3) * 1024 + l * 16);
            rb0 = wbias[(gt0 + 0) * 16 + l15];
            rb1 = wbias[(gt0 + 1) * 16 + l15];
            rb2 = wbias[(gt0 + 2) * 16 + l15];
            rb3 = wbias[(gt0 + 3) * 16 + l15];
        }

        // ---- J half: 2 tiles of group 64+a_sh (registers, it-invariant) ----
        {
            float ej0 = 0.f, ej1 = 0.f, ej2 = 0.f, ej3 = 0.f;
            const int mp = a_sh ^ sx;
#pragma unroll
            for (int s = 0; s < 2; ++s) {
                const int tt = tb + s;
                const float bv = (s == 0) ? bj0 : bj1;
                f32x4 acc = {bv, bv, bv, bv};
                acc = MFMA16(af.v, (s == 0) ? tj0.v : tj1.v, acc);
                const float e0 = EXP2(acc[0]), e1 = EXP2(acc[1]);
                const float e2 = EXP2(acc[2]), e3 = EXP2(acc[3]);
                const int kk = (tt << 4) + l15;
                JT[q * 4 + 0][kk][mp] = (__fp16)e0;
                JT[q * 4 + 1][kk][mp] = (__fp16)e1;
                JT[q * 4 + 2][kk][mp] = (__fp16)e2;
                JT[q * 4 + 3][kk][mp] = (__fp16)e3;
                ej0 += e0; ej1 += e1; ej2 += e2; ej3 += e3;
            }
            ej0 = sum16_all(ej0); ej1 = sum16_all(ej1);
            ej2 = sum16_all(ej2); ej3 = sum16_all(ej3);
            if (l15 == 0) {
                ph[w][q * 4 + 0] = ej0;
                ph[w][q * 4 + 1] = ej1;
                ph[w][q * 4 + 2] = ej2;
                ph[w][q * 4 + 3] = ej3;
            }
        }
        __syncthreads();   // barrier A: ph visible

        // ---- J finalize (moved up: overlaps R compute; xj read after B) ----
        if ((w & 1) == 0 && l15 == 0) {
#pragma unroll
            for (int r = 0; r < 4; ++r) {
                const int t = q * 4 + r;
                const float tot = ph[w][t] + ph[w + 1][t];
                xj[t][a_sh ^ sx] =
                    (__fp16)(xm_lds[it * 16 + t][a_sh] * __builtin_amdgcn_rcpf(tot));
            }
        }

        // ---- 4 full R groups, depth-1 pipelined; outer unroll 1 ----
#pragma unroll 1
        for (int g = 0; g < 4; ++g) {
            const int gg = w * 4 + g;                    // 0..63
            // issue next group's loads before this group's compute
            V8 n0, n1, n2, n3; float a0, a1, a2, a3;
            if (g != 3) {
                const int gtn = (gg + 1) * 4;
                n0.i = *(const i32x4*)(wsb + (size_t)(gtn + 0) * 1024 + l * 16);
                n1.i = *(const i32x4*)(wsb + (size_t)(gtn + 1) * 1024 + l * 16);
                n2.i = *(const i32x4*)(wsb + (size_t)(gtn + 2) * 1024 + l * 16);
                n3.i = *(const i32x4*)(wsb + (size_t)(gtn + 3) * 1024 + l * 16);
                a0 = wbias[(gtn + 0) * 16 + l15];
                a1 = wbias[(gtn + 1) * 16 + l15];
                a2 = wbias[(gtn + 2) * 16 + l15];
                a3 = wbias[(gtn + 3) * 16 + l15];
            }
            const int hb = gg >> 3, p = (gg & 7) ^ sx;   // swizzled slot
            float es0 = 0.f, es1 = 0.f, es2 = 0.f, es3 = 0.f;
            R_TILE(rc0, rb0, 0);
            R_TILE(rc1, rb1, 1);
            R_TILE(rc2, rb2, 2);
            R_TILE(rc3, rb3, 3);
            const float sr0 = sum16_all(es0), sr1 = sum16_all(es1);
            const float sr2 = sum16_all(es2), sr3 = sum16_all(es3);
            if (l15 == 0) {
                sinv[q * 4 + 0][gg] = __builtin_amdgcn_rcpf(sr0);
                sinv[q * 4 + 1][gg] = __builtin_amdgcn_rcpf(sr1);
                sinv[q * 4 + 2][gg] = __builtin_amdgcn_rcpf(sr2);
                sinv[q * 4 + 3][gg] = __builtin_amdgcn_rcpf(sr3);
            }
            rc0 = n0; rc1 = n1; rc2 = n2; rc3 = n3;
            rb0 = a0; rb1 = a1; rb2 = a2; rb3 = a3;
        }
        __syncthreads();   // barrier B: produce complete

        // ====== m_in pass (parallel, c-independent): minL[t][k] = xj[t].JT[t][k] ======
        // JT and xj carry the SAME (w>>2)-dependent k-permutation inside each
        // 16B chunk, so the dot2 pairs still line up.
        {
            V8 jv; jv.v = *(const f16x8*)&JT[w][l][0];
            V8 xv; xv.v = *(const f16x8*)&xj[w][0];
            float s = 0.f;
            s = dot2(jv.p[0], xv.p[0], s);
            s = dot2(jv.p[1], xv.p[1], s);
            s = dot2(jv.p[2], xv.p[2], s);
            s = dot2(jv.p[3], xv.p[3], s);
            minL[w][l] = (__fp16)s;
        }
        __syncthreads();   // barrier C

        // ================= scan: 16 serial MFMA matvecs (wave 15) =================
        // cbuf-free: chat pair-packed in-register (RNE), redistributed by
        // bpermute from the SERVING lane (lane 2P holds chat pair P).
        if (w == 15) {
            const int ab = q << 5;              // A0 byte base = lane 8q
            for (int u = 0; u < 16; ++u) {
                const int sig = (u >> 2) & 3;   // matches producer swizzle
                // ---- c-independent prefetch (no fences -> compiler pipelines) ----
                const float mi0 = (float)minL[u][l15];
                const float mi1 = (float)minL[u][16 + l15];
                const float mi2 = (float)minL[u][32 + l15];
                const float mi3 = (float)minL[u][48 + l15];
                const float svl = sinv[u][l];
                V8 b00, b01, b10, b11, b20, b21, b30, b31;
                b00.v = *(const f16x8*)&RT[u][q][l15][0];
                b01.v = *(const f16x8*)&RT[u][4 + q][l15][0];
                b10.v = *(const f16x8*)&RT[u][q][16 + l15][0];
                b11.v = *(const f16x8*)&RT[u][4 + q][16 + l15][0];
                b20.v = *(const f16x8*)&RT[u][q][32 + l15][0];
                b21.v = *(const f16x8*)&RT[u][4 + q][32 + l15][0];
                b30.v = *(const f16x8*)&RT[u][q][48 + l15][0];
                b31.v = *(const f16x8*)&RT[u][4 + q][48 + l15][0];
                // ---- chat_l = c[l] * sinv[u][l]  (the r15 cbuf value, in-reg) ----
                const float cown = (q == 0) ? c0 : (q == 1) ? c1 : (q == 2) ? c2 : c3;
                const int spk = pack_pair_rne(cown * svl);  // lane pair 2P,2P+1 -> chat pair P
                // ---- A-frags via bpermute: A0 pair jp <- lane 8q+2(jp^sig);
                //      A1 pair jp <- lane 32+8q+2(jp^sig) (offset 128 folds) ----
                V8 A0f, A1f;
                A0f.i[0] = __builtin_amdgcn_ds_bpermute(ab + ((0 ^ sig) << 3), spk);
                A0f.i[1] = __builtin_amdgcn_ds_bpermute(ab + ((1 ^ sig) << 3), spk);
                A0f.i[2] = __builtin_amdgcn_ds_bpermute(ab + ((2 ^ sig) << 3), spk);
                A0f.i[3] = __builtin_amdgcn_ds_bpermute(ab + ((3 ^ sig) << 3), spk);
                A1f.i[0] = __builtin_amdgcn_ds_bpermute(128 + ab + ((0 ^ sig) << 3), spk);
                A1f.i[1] = __builtin_amdgcn_ds_bpermute(128 + ab + ((1 ^ sig) << 3), spk);
                A1f.i[2] = __builtin_amdgcn_ds_bpermute(128 + ab + ((2 ^ sig) << 3), spk);
                A1f.i[3] = __builtin_amdgcn_ds_bpermute(128 + ab + ((3 ^ sig) << 3), spk);
                // ---- 2-deep MFMA chains, C-init = m_in ----
                f32x4 a0 = {mi0, mi0, mi0, mi0};
                a0 = MFMA16(A0f.v, b00.v, a0);
                a0 = MFMA16(A1f.v, b01.v, a0);
                f32x4 a1 = {mi1, mi1, mi1, mi1};
                a1 = MFMA16(A0f.v, b10.v, a1);
                a1 = MFMA16(A1f.v, b11.v, a1);
                f32x4 a2 = {mi2, mi2, mi2, mi2};
                a2 = MFMA16(A0f.v, b20.v, a2);
                a2 = MFMA16(A1f.v, b21.v, a2);
                f32x4 a3 = {mi3, mi3, mi3, mi3};
                a3 = MFMA16(A0f.v, b30.v, a3);
                a3 = MFMA16(A1f.v, b31.v, a3);
                c0 = a0[0]; c1 = a1[0]; c2 = a2[0]; c3 = a3[0];
            }
        }
        __syncthreads();   // barrier D
    }

    // ---- epilogue: out = (sigmoid(xa_T@Wo+bo) * c_T) @ Wfc + bfc ----
    if (w == 15) {
        const float cown = (q == 0) ? c0 : (q == 1) ? c1 : (q == 2) ? c2 : c3;
        cfin_lds[l] = cown;                              // all-lane write
        LDS_FENCE();
        const float* xa = x_a + ((size_t)b * T_ + (T_ - 1)) * AUX_;
        float L = bo[l];
#pragma unroll
        for (int a = 0; a < AUX_; ++a) L = fmaf(xa[a], Wo[a * H_ + l], L);
        const float o = 1.0f / (1.0f + __expf(-L));
        const float cfin = cfin_lds[l];
        float p = (o * cfin) * Wfc[l];
        p = sum64_uni(p);
        if (l == 0) out[b] = p + bfc[0];
        out[B_ + b * H_ + l] = cfin;                     // c_final, coalesced
    }
}

} // namespace

extern "C" void kernel_launch(void* const* d_in, const int* in_sizes, int n_in,
                              void* d_out, int out_size, void* d_ws, size_t ws_size,
                              hipStream_t stream) {
    const float* x_m = (const float*)d_in[0];
    const float* x_a = (const float*)d_in[1];
    const float* Wj  = (const float*)d_in[2];
    const float* bj  = (const float*)d_in[3];
    const float* Wr  = (const float*)d_in[4];
    const float* br  = (const float*)d_in[5];
    const float* Wo  = (const float*)d_in[6];
    const float* bo  = (const float*)d_in[7];
    const float* Wfc = (const float*)d_in[8];
    const float* bfc = (const float*)d_in[9];
    float* out = (float*)d_out;

    hipLaunchKernelGGL(nomc_prep, dim3(NTILE), dim3(64), 0, stream,
                       Wj, bj, Wr, br, d_ws);
    hipLaunchKernelGGL(nomc_main, dim3(B_), dim3(1024), 0, stream,
                       x_m, x_a, Wo, bo, Wfc, bfc, d_ws, out);
}

// Round 9
// 234.626 us; speedup vs baseline: 1.0865x; 1.0865x over previous
//
#include <hip/hip_runtime.h>

// NoMCOutModel round 23: r22's depth-1 pipeline + amdgpu_waves_per_eu(4,4)
// to unpin the register allocator.
// r22 post-mortem: WRITE 72KB -> 11.3MB, FETCH +3MB, VGPR pinned at 64 ->
// scratch again. Session pattern: every kernel needing >64 VGPR (r15, r19,
// r20, r22) pins at exactly 64 and spills; the allocator targets the
// 64-VGPR / 8-waves-per-SIMD occupancy step even though LDS (163KB) caps
// this kernel at 1 block/CU = 4 waves/SIMD, where the true budget is
// 512/4 = 128 VGPR. __launch_bounds__' 2nd arg is only a MIN; it never
// raises the allocator's target. Fix: amdgpu_waves_per_eu(4,4) pins
// min=max=4 -> 128-VGPR budget -> the ~100-VGPR pipeline fits.
// Pipeline (steady-state rotation): group-0 tiles preloaded ONCE before
// the it loop; group g's compute overlaps the loads of group (g+1)&3
// (g=3 fetches group 0 for the NEXT it -- addresses are it-invariant).
// J tiles/biases it-invariant in regs (r22). Everything else: r21/r18.

namespace {

constexpr int B_ = 256, T_ = 256, M_ = 8, AUX_ = 32, H_ = 64;
constexpr int NTILE = 288;               // (64*64 + 8*64)/16 logit col-tiles
constexpr float LOG2E = 1.4426950408889634f;

typedef __fp16 f16x2 __attribute__((ext_vector_type(2)));
typedef __fp16 f16x8 __attribute__((ext_vector_type(8)));
typedef float  f32x4 __attribute__((ext_vector_type(4)));
typedef int    i32x4 __attribute__((ext_vector_type(4)));

union V8 { f16x8 v; f16x2 p[4]; i32x4 i; };

#if __has_builtin(__builtin_amdgcn_exp2f)
#define EXP2(x) __builtin_amdgcn_exp2f(x)
#else
#define EXP2(x) exp2f(x)
#endif

#define MFMA16(A, Bv, C) __builtin_amdgcn_mfma_f32_16x16x32_f16((A), (Bv), (C), 0, 0, 0)

__device__ __forceinline__ float dot2(f16x2 a, f16x2 b, float c) {
    return __builtin_amdgcn_fdot2(a, b, c, false);
}

template <int CTRL>
__device__ __forceinline__ float dpp_add(float v) {
    int t = __builtin_amdgcn_update_dpp(0, __builtin_bit_cast(int, v),
                                        CTRL, 0xf, 0xf, true);
    return v + __builtin_bit_cast(float, t);
}
__device__ __forceinline__ float sum16_all(float v) {
    v = dpp_add<0xB1>(v);   // quad_perm [1,0,3,2]
    v = dpp_add<0x4E>(v);   // quad_perm [2,3,0,1]
    v = dpp_add<0x141>(v);  // row_half_mirror
    v = dpp_add<0x140>(v);  // row_mirror
    return v;
}
__device__ __forceinline__ float sum64_uni(float v) {
    v = dpp_add<0x111>(v); v = dpp_add<0x112>(v); v = dpp_add<0x114>(v);
    v = dpp_add<0x118>(v); v = dpp_add<0x142>(v); v = dpp_add<0x143>(v);
    return __builtin_bit_cast(float,
        __builtin_amdgcn_readlane(__builtin_bit_cast(int, v), 63));
}

// RNE pair-pack: every lane ends with (f16(chat[2P]), f16(chat[2P+1])) where
// P = lane>>1. Own value is converted RNE ((__fp16) cast = v_cvt_f16_f32),
// then quad_perm DPP broadcasts the even/odd pair members to both lanes.
__device__ __forceinline__ int pack_pair_rne(float v) {
    const int hv = (int)__builtin_bit_cast(unsigned short, (__fp16)v);
    const int ev = __builtin_amdgcn_update_dpp(0, hv, 0xA0, 0xf, 0xf, true); // [0,0,2,2]
    const int ov = __builtin_amdgcn_update_dpp(0, hv, 0xF5, 0xf, 0xf, true); // [1,1,3,3]
    return ev | (ov << 16);
}

#define LDS_FENCE() __asm__ volatile("s_waitcnt lgkmcnt(0)" ::: "memory")

// ---------------- prep: W -> f16 MFMA B-frag layout in ws ----------------
// ws[gt*1024 + lane*16] : f16x8 frag, B[k = (lane>>4)*8 + j][n = gt*16+(lane&15)]
// ws + 288*1024 : float bias[4608] (log2e-scaled)
__global__ __launch_bounds__(64)
void nomc_prep(const float* __restrict__ Wj, const float* __restrict__ bj,
               const float* __restrict__ Wr, const float* __restrict__ br,
               void* __restrict__ ws)
{
    const int gt = blockIdx.x;           // 0..287
    const int l = threadIdx.x, q = l >> 4, l15 = l & 15;
    const float* src; const float* bsrc; int stride;
    if (gt < 256) { const int n = gt * 16 + l15;        src = Wr + n; bsrc = br + n; stride = 4096; }
    else          { const int n = (gt - 256) * 16 + l15; src = Wj + n; bsrc = bj + n; stride = 512; }
    V8 v;
#pragma unroll
    for (int j = 0; j < 4; ++j) {
        const float f0 = src[(q * 8 + 2 * j)     * stride] * LOG2E;
        const float f1 = src[(q * 8 + 2 * j + 1) * stride] * LOG2E;
        v.p[j] = __builtin_amdgcn_cvt_pkrtz(f0, f1);
    }
    *(i32x4*)((char*)ws + (size_t)gt * 1024 + l * 16) = v.i;
    if (l < 16)
        ((float*)((char*)ws + NTILE * 1024))[gt * 16 + l] = bsrc[0] * LOG2E;
}

// one R tile: MFMA -> exp2 -> swizzled RT stores -> rowsum accumulate
#define R_TILE(BF, BV, TT)                                                   \
    do {                                                                     \
        f32x4 acc = {(BV), (BV), (BV), (BV)};                                \
        acc = MFMA16(af.v, (BF).v, acc);                                     \
        const float e0 = EXP2(acc[0]), e1 = EXP2(acc[1]);                    \
        const float e2 = EXP2(acc[2]), e3 = EXP2(acc[3]);                    \
        const int kk = ((TT) << 4) + l15;                                    \
        RT[q * 4 + 0][hb][kk][p] = (__fp16)e0;                               \
        RT[q * 4 + 1][hb][kk][p] = (__fp16)e1;                               \
        RT[q * 4 + 2][hb][kk][p] = (__fp16)e2;                               \
        RT[q * 4 + 3][hb][kk][p] = (__fp16)e3;                               \
        es0 += e0; es1 += e1; es2 += e2; es3 += e3;                          \
    } while (0)

// ---------------- main ----------------
__global__ __launch_bounds__(1024)
__attribute__((amdgpu_waves_per_eu(4, 4)))
void nomc_main(const float* __restrict__ x_m, const float* __restrict__ x_a,
               const float* __restrict__ Wo, const float* __restrict__ bo,
               const float* __restrict__ Wfc, const float* __restrict__ bfc,
               const void* __restrict__ ws, float* __restrict__ out)
{
    const int b = blockIdx.x, tid = threadIdx.x;
    const int w = tid >> 6, l = tid & 63, q = l >> 4, l15 = l & 15;

    __shared__ __align__(16) __fp16 RT[16][8][64][8];   // 131072 B  RT[t][h>>3][k][(h&7)^((t>>2)<<1)]=e
    __shared__ __align__(16) __fp16 JT[16][64][8];      //  16384 B  JT[t][k][m^((t>>2)<<1)]=e_j
    __shared__ float sinv[16][64];                      //   4096 B  1/rowsum(R)
    __shared__ __align__(16) __fp16 xj[16][8];          //    256 B  [t][m^((t>>2)<<1)]=xm/s_j
    __shared__ __align__(16) __fp16 minL[16][64];       //   2048 B  m_in[t][k]
    __shared__ float xm_lds[T_][M_];                    //   8192 B
    __shared__ float cfin_lds[H_];                      //    256 B
    __shared__ float ph[16][16];                        //   1024 B  J half-rowsums [wave][t]
    // total 163328 <= 163840

    {   // stage x_m once
        const float* xmb = x_m + (size_t)b * T_ * M_;
        for (int i = tid; i < T_ * M_; i += 1024) (&xm_lds[0][0])[i] = xmb[i];
    }
    __syncthreads();

    // Balanced produce: wave w owns R groups {4w..4w+3} (16 tiles) + half of
    // J group 64+(w>>1): tiles tt in {0,1} for even w, {2,3} for odd w.
    const char* wsb = (const char*)ws;
    const float* wbias = (const float*)(wsb + NTILE * 1024);
    const int a_sh = w >> 1;                 // shared J group -> m = a_sh
    const int tb = (w & 1) ? 2 : 0;          // J tile base

    const int sx = q << 1;               // store-side bank swizzle (= (t>>2)<<1)

    // ---- it-invariant J tiles + biases (addresses = f(w) only) ----
    V8 tj0, tj1; float bj0, bj1;
    {
        const int gtj = (64 + a_sh) * 4 + tb;
        tj0.i = *(const i32x4*)(wsb + (size_t)(gtj + 0) * 1024 + l * 16);
        tj1.i = *(const i32x4*)(wsb + (size_t)(gtj + 1) * 1024 + l * 16);
        bj0 = wbias[(gtj + 0) * 16 + l15];
        bj1 = wbias[(gtj + 1) * 16 + l15];
    }

    // ---- steady-state pipeline registers: preload R group 0 once ----
    V8 rc0, rc1, rc2, rc3; float rb0, rb1, rb2, rb3;
    {
        const int gt0 = (w * 4) * 4;
        rc0.i = *(const i32x4*)(wsb + (size_t)(gt0 + 0) * 1024 + l * 16);
        rc1.i = *(const i32x4*)(wsb + (size_t)(gt0 + 1) * 1024 + l * 16);
        rc2.i = *(const i32x4*)(wsb + (size_t)(gt0 + 2) * 1024 + l * 16);
        rc3.i = *(const i32x4*)(wsb + (size_t)(gt0 + 3) * 1024 + l * 16);
        rb0 = wbias[(gt0 + 0) * 16 + l15];
        rb1 = wbias[(gt0 + 1) * 16 + l15];
        rb2 = wbias[(gt0 + 2) * 16 + l15];
        rb3 = wbias[(gt0 + 3) * 16 + l15];
    }

    float c0 = 0.f, c1 = 0.f, c2 = 0.f, c3 = 0.f;   // c[kt*16 + l15], q-replicated

    for (int it = 0; it < 16; ++it) {
        // ================= produce: 16 timesteps of exp(logits) =================
        V8 af;
        {   // A-frag: row = l15 -> t = it*16+l15; k = q*8+j
            const float* xa = x_a + ((size_t)b * T_ + it * 16 + l15) * AUX_ + q * 8;
            const f32x4 x0 = *(const f32x4*)xa;
            const f32x4 x1 = *(const f32x4*)(xa + 4);
            af.p[0] = __builtin_amdgcn_cvt_pkrtz(x0.x, x0.y);
            af.p[1] = __builtin_amdgcn_cvt_pkrtz(x0.z, x0.w);
            af.p[2] = __builtin_amdgcn_cvt_pkrtz(x1.x, x1.y);
            af.p[3] = __builtin_amdgcn_cvt_pkrtz(x1.z, x1.w);
        }

        // ---- J half: 2 tiles of group 64+a_sh (registers, it-invariant) ----
        {
            float ej0 = 0.f, ej1 = 0.f, ej2 = 0.f, ej3 = 0.f;
            const int mp = a_sh ^ sx;
#pragma unroll
            for (int s = 0; s < 2; ++s) {
                const int tt = tb + s;
                const float bv = (s == 0) ? bj0 : bj1;
                f32x4 acc = {bv, bv, bv, bv};
                acc = MFMA16(af.v, (s == 0) ? tj0.v : tj1.v, acc);
                const float e0 = EXP2(acc[0]), e1 = EXP2(acc[1]);
                const float e2 = EXP2(acc[2]), e3 = EXP2(acc[3]);
                const int kk = (tt << 4) + l15;
                JT[q * 4 + 0][kk][mp] = (__fp16)e0;
                JT[q * 4 + 1][kk][mp] = (__fp16)e1;
                JT[q * 4 + 2][kk][mp] = (__fp16)e2;
                JT[q * 4 + 3][kk][mp] = (__fp16)e3;
                ej0 += e0; ej1 += e1; ej2 += e2; ej3 += e3;
            }
            ej0 = sum16_all(ej0); ej1 = sum16_all(ej1);
            ej2 = sum16_all(ej2); ej3 = sum16_all(ej3);
            if (l15 == 0) {
                ph[w][q * 4 + 0] = ej0;
                ph[w][q * 4 + 1] = ej1;
                ph[w][q * 4 + 2] = ej2;
                ph[w][q * 4 + 3] = ej3;
            }
        }
        __syncthreads();   // barrier A: ph visible

        // ---- J finalize (overlaps R compute; xj read after barrier B) ----
        if ((w & 1) == 0 && l15 == 0) {
#pragma unroll
            for (int r = 0; r < 4; ++r) {
                const int t = q * 4 + r;
                const float tot = ph[w][t] + ph[w + 1][t];
                xj[t][a_sh ^ sx] =
                    (__fp16)(xm_lds[it * 16 + t][a_sh] * __builtin_amdgcn_rcpf(tot));
            }
        }

        // ---- 4 full R groups, steady-state depth-1 rotation ----
#pragma unroll 1
        for (int g = 0; g < 4; ++g) {
            const int gg = w * 4 + g;                    // 0..63
            // issue NEXT slot's loads first (g=3 -> group 0 for next it)
            const int gtn = (w * 4 + ((g + 1) & 3)) * 4;
            V8 n0, n1, n2, n3; float a0, a1, a2, a3;
            n0.i = *(const i32x4*)(wsb + (size_t)(gtn + 0) * 1024 + l * 16);
            n1.i = *(const i32x4*)(wsb + (size_t)(gtn + 1) * 1024 + l * 16);
            n2.i = *(const i32x4*)(wsb + (size_t)(gtn + 2) * 1024 + l * 16);
            n3.i = *(const i32x4*)(wsb + (size_t)(gtn + 3) * 1024 + l * 16);
            a0 = wbias[(gtn + 0) * 16 + l15];
            a1 = wbias[(gtn + 1) * 16 + l15];
            a2 = wbias[(gtn + 2) * 16 + l15];
            a3 = wbias[(gtn + 3) * 16 + l15];
            const int hb = gg >> 3, p = (gg & 7) ^ sx;   // swizzled slot
            float es0 = 0.f, es1 = 0.f, es2 = 0.f, es3 = 0.f;
            R_TILE(rc0, rb0, 0);
            R_TILE(rc1, rb1, 1);
            R_TILE(rc2, rb2, 2);
            R_TILE(rc3, rb3, 3);
            const float sr0 = sum16_all(es0), sr1 = sum16_all(es1);
            const float sr2 = sum16_all(es2), sr3 = sum16_all(es3);
            if (l15 == 0) {
                sinv[q * 4 + 0][gg] = __builtin_amdgcn_rcpf(sr0);
                sinv[q * 4 + 1][gg] = __builtin_amdgcn_rcpf(sr1);
                sinv[q * 4 + 2][gg] = __builtin_amdgcn_rcpf(sr2);
                sinv[q * 4 + 3][gg] = __builtin_amdgcn_rcpf(sr3);
            }
            rc0 = n0; rc1 = n1; rc2 = n2; rc3 = n3;
            rb0 = a0; rb1 = a1; rb2 = a2; rb3 = a3;
        }
        __syncthreads();   // barrier B: produce complete

        // ====== m_in pass (parallel, c-independent): minL[t][k] = xj[t].JT[t][k] ======
        // JT and xj carry the SAME (w>>2)-dependent k-permutation inside each
        // 16B chunk, so the dot2 pairs still line up.
        {
            V8 jv; jv.v = *(const f16x8*)&JT[w][l][0];
            V8 xv; xv.v = *(const f16x8*)&xj[w][0];
            float s = 0.f;
            s = dot2(jv.p[0], xv.p[0], s);
            s = dot2(jv.p[1], xv.p[1], s);
            s = dot2(jv.p[2], xv.p[2], s);
            s = dot2(jv.p[3], xv.p[3], s);
            minL[w][l] = (__fp16)s;
        }
        __syncthreads();   // barrier C

        // ================= scan: 16 serial MFMA matvecs (wave 15) =================
        // cbuf-free: chat pair-packed in-register (RNE), redistributed by
        // bpermute from the SERVING lane (lane 2P holds chat pair P).
        if (w == 15) {
            const int ab = q << 5;              // A0 byte base = lane 8q
            for (int u = 0; u < 16; ++u) {
                const int sig = (u >> 2) & 3;   // matches producer swizzle
                // ---- c-independent prefetch (no fences -> compiler pipelines) ----
                const float mi0 = (float)minL[u][l15];
                const float mi1 = (float)minL[u][16 + l15];
                const float mi2 = (float)minL[u][32 + l15];
                const float mi3 = (float)minL[u][48 + l15];
                const float svl = sinv[u][l];
                V8 b00, b01, b10, b11, b20, b21, b30, b31;
                b00.v = *(const f16x8*)&RT[u][q][l15][0];
                b01.v = *(const f16x8*)&RT[u][4 + q][l15][0];
                b10.v = *(const f16x8*)&RT[u][q][16 + l15][0];
                b11.v = *(const f16x8*)&RT[u][4 + q][16 + l15][0];
                b20.v = *(const f16x8*)&RT[u][q][32 + l15][0];
                b21.v = *(const f16x8*)&RT[u][4 + q][32 + l15][0];
                b30.v = *(const f16x8*)&RT[u][q][48 + l15][0];
                b31.v = *(const f16x8*)&RT[u][4 + q][48 + l15][0];
                // ---- chat_l = c[l] * sinv[u][l]  (the r15 cbuf value, in-reg) ----
                const float cown = (q == 0) ? c0 : (q == 1) ? c1 : (q == 2) ? c2 : c3;
                const int spk = pack_pair_rne(cown * svl);  // lane pair 2P,2P+1 -> chat pair P
                // ---- A-frags via bpermute: A0 pair jp <- lane 8q+2(jp^sig);
                //      A1 pair jp <- lane 32+8q+2(jp^sig) (offset 128 folds) ----
                V8 A0f, A1f;
                A0f.i[0] = __builtin_amdgcn_ds_bpermute(ab + ((0 ^ sig) << 3), spk);
                A0f.i[1] = __builtin_amdgcn_ds_bpermute(ab + ((1 ^ sig) << 3), spk);
                A0f.i[2] = __builtin_amdgcn_ds_bpermute(ab + ((2 ^ sig) << 3), spk);
                A0f.i[3] = __builtin_amdgcn_ds_bpermute(ab + ((3 ^ sig) << 3), spk);
                A1f.i[0] = __builtin_amdgcn_ds_bpermute(128 + ab + ((0 ^ sig) << 3), spk);
                A1f.i[1] = __builtin_amdgcn_ds_bpermute(128 + ab + ((1 ^ sig) << 3), spk);
                A1f.i[2] = __builtin_amdgcn_ds_bpermute(128 + ab + ((2 ^ sig) << 3), spk);
                A1f.i[3] = __builtin_amdgcn_ds_bpermute(128 + ab + ((3 ^ sig) << 3), spk);
                // ---- 2-deep MFMA chains, C-init = m_in ----
                f32x4 a0 = {mi0, mi0, mi0, mi0};
                a0 = MFMA16(A0f.v, b00.v, a0);
                a0 = MFMA16(A1f.v, b01.v, a0);
                f32x4 a1 = {mi1, mi1, mi1, mi1};
                a1 = MFMA16(A0f.v, b10.v, a1);
                a1 = MFMA16(A1f.v, b11.v, a1);
                f32x4 a2 = {mi2, mi2, mi2, mi2};
                a2 = MFMA16(A0f.v, b20.v, a2);
                a2 = MFMA16(A1f.v, b21.v, a2);
                f32x4 a3 = {mi3, mi3, mi3, mi3};
                a3 = MFMA16(A0f.v, b30.v, a3);
                a3 = MFMA16(A1f.v, b31.v, a3);
                c0 = a0[0]; c1 = a1[0]; c2 = a2[0]; c3 = a3[0];
            }
        }
        __syncthreads();   // barrier D
    }

    // ---- epilogue: out = (sigmoid(xa_T@Wo+bo) * c_T) @ Wfc + bfc ----
    if (w == 15) {
        const float cown = (q == 0) ? c0 : (q == 1) ? c1 : (q == 2) ? c2 : c3;
        cfin_lds[l] = cown;                              // all-lane write
        LDS_FENCE();
        const float* xa = x_a + ((size_t)b * T_ + (T_ - 1)) * AUX_;
        float L = bo[l];
#pragma unroll
        for (int a = 0; a < AUX_; ++a) L = fmaf(xa[a], Wo[a * H_ + l], L);
        const float o = 1.0f / (1.0f + __expf(-L));
        const float cfin = cfin_lds[l];
        float p = (o * cfin) * Wfc[l];
        p = sum64_uni(p);
        if (l == 0) out[b] = p + bfc[0];
        out[B_ + b * H_ + l] = cfin;                     // c_final, coalesced
    }
}

} // namespace

extern "C" void kernel_launch(void* const* d_in, const int* in_sizes, int n_in,
                              void* d_out, int out_size, void* d_ws, size_t ws_size,
                              hipStream_t stream) {
    const float* x_m = (const float*)d_in[0];
    const float* x_a = (const float*)d_in[1];
    const float* Wj  = (const float*)d_in[2];
    const float* bj  = (const float*)d_in[3];
    const float* Wr  = (const float*)d_in[4];
    const float* br  = (const float*)d_in[5];
    const float* Wo  = (const float*)d_in[6];
    const float* bo  = (const float*)d_in[7];
    const float* Wfc = (const float*)d_in[8];
    const float* bfc = (const float*)d_in[9];
    float* out = (float*)d_out;

    hipLaunchKernelGGL(nomc_prep, dim3(NTILE), dim3(64), 0, stream,
                       Wj, bj, Wr, br, d_ws);
    hipLaunchKernelGGL(nomc_main, dim3(B_), dim3(1024), 0, stream,
                       x_m, x_a, Wo, bo, Wfc, bfc, d_ws, out);
}

// Round 10
// 234.533 us; speedup vs baseline: 1.0869x; 1.0004x over previous
//
#include <hip/hip_runtime.h>

// NoMCOutModel round 24: hide the J phase (+its barrier) under the serial
// scan. r23 post-mortem: depth-1 rotation neutral (VALUBusy 41->45.6, time
// unchanged, VGPR pinned 64) -> produce is not load-latency-bound; the
// remaining structural waste is the scan window where 15/16 waves idle.
// J work has NO dependency on scan buffers (RT/sinv/minL): JT(it+1),
// ph(it+1), xj[.][7](it+1), af(it+1) are all computed during scan(it).
// Rebalance: waves 0..13 pair-split J groups 0..6 (2 tiles each); wave 14
// owns J group 7 alone (full rowsum -> writes xj[.][7] directly, no ph);
// wave 15 has NO J duty. All 16 waves: exactly 4 R groups. Pair J-finalize
// (ph merge -> xj) runs at it-top before the R phase. Barrier A is gone
// (3 barriers/it). J tiles JIT-loaded in the overlap region (L2 latency
// free under scan) -- drops the cached tj regs. Lifetimes: JT(it) dead
// after m_in(it) (barrier C precedes overlap writes); ph(it) consumed at
// it-top; af persists in regs across barrier D. Prologue runs J(0)+af(0).
// launch_bounds swapped for flat_work_group_size(1024,1024)+waves_per_eu
// (4,4) (exact-occupancy info to the allocator).
// R-phase/m_in/scan/prep/epilogue: identical to r23.

namespace {

constexpr int B_ = 256, T_ = 256, M_ = 8, AUX_ = 32, H_ = 64;
constexpr int NTILE = 288;               // (64*64 + 8*64)/16 logit col-tiles
constexpr float LOG2E = 1.4426950408889634f;

typedef __fp16 f16x2 __attribute__((ext_vector_type(2)));
typedef __fp16 f16x8 __attribute__((ext_vector_type(8)));
typedef float  f32x4 __attribute__((ext_vector_type(4)));
typedef int    i32x4 __attribute__((ext_vector_type(4)));

union V8 { f16x8 v; f16x2 p[4]; i32x4 i; };

#if __has_builtin(__builtin_amdgcn_exp2f)
#define EXP2(x) __builtin_amdgcn_exp2f(x)
#else
#define EXP2(x) exp2f(x)
#endif

#define MFMA16(A, Bv, C) __builtin_amdgcn_mfma_f32_16x16x32_f16((A), (Bv), (C), 0, 0, 0)

__device__ __forceinline__ float dot2(f16x2 a, f16x2 b, float c) {
    return __builtin_amdgcn_fdot2(a, b, c, false);
}

template <int CTRL>
__device__ __forceinline__ float dpp_add(float v) {
    int t = __builtin_amdgcn_update_dpp(0, __builtin_bit_cast(int, v),
                                        CTRL, 0xf, 0xf, true);
    return v + __builtin_bit_cast(float, t);
}
__device__ __forceinline__ float sum16_all(float v) {
    v = dpp_add<0xB1>(v);   // quad_perm [1,0,3,2]
    v = dpp_add<0x4E>(v);   // quad_perm [2,3,0,1]
    v = dpp_add<0x141>(v);  // row_half_mirror
    v = dpp_add<0x140>(v);  // row_mirror
    return v;
}
__device__ __forceinline__ float sum64_uni(float v) {
    v = dpp_add<0x111>(v); v = dpp_add<0x112>(v); v = dpp_add<0x114>(v);
    v = dpp_add<0x118>(v); v = dpp_add<0x142>(v); v = dpp_add<0x143>(v);
    return __builtin_bit_cast(float,
        __builtin_amdgcn_readlane(__builtin_bit_cast(int, v), 63));
}

// RNE pair-pack: every lane ends with (f16(chat[2P]), f16(chat[2P+1])) where
// P = lane>>1. Own value is converted RNE ((__fp16) cast = v_cvt_f16_f32),
// then quad_perm DPP broadcasts the even/odd pair members to both lanes.
__device__ __forceinline__ int pack_pair_rne(float v) {
    const int hv = (int)__builtin_bit_cast(unsigned short, (__fp16)v);
    const int ev = __builtin_amdgcn_update_dpp(0, hv, 0xA0, 0xf, 0xf, true); // [0,0,2,2]
    const int ov = __builtin_amdgcn_update_dpp(0, hv, 0xF5, 0xf, 0xf, true); // [1,1,3,3]
    return ev | (ov << 16);
}

#define LDS_FENCE() __asm__ volatile("s_waitcnt lgkmcnt(0)" ::: "memory")

// ---------------- prep: W -> f16 MFMA B-frag layout in ws ----------------
// ws[gt*1024 + lane*16] : f16x8 frag, B[k = (lane>>4)*8 + j][n = gt*16+(lane&15)]
// ws + 288*1024 : float bias[4608] (log2e-scaled)
__global__ __launch_bounds__(64)
void nomc_prep(const float* __restrict__ Wj, const float* __restrict__ bj,
               const float* __restrict__ Wr, const float* __restrict__ br,
               void* __restrict__ ws)
{
    const int gt = blockIdx.x;           // 0..287
    const int l = threadIdx.x, q = l >> 4, l15 = l & 15;
    const float* src; const float* bsrc; int stride;
    if (gt < 256) { const int n = gt * 16 + l15;        src = Wr + n; bsrc = br + n; stride = 4096; }
    else          { const int n = (gt - 256) * 16 + l15; src = Wj + n; bsrc = bj + n; stride = 512; }
    V8 v;
#pragma unroll
    for (int j = 0; j < 4; ++j) {
        const float f0 = src[(q * 8 + 2 * j)     * stride] * LOG2E;
        const float f1 = src[(q * 8 + 2 * j + 1) * stride] * LOG2E;
        v.p[j] = __builtin_amdgcn_cvt_pkrtz(f0, f1);
    }
    *(i32x4*)((char*)ws + (size_t)gt * 1024 + l * 16) = v.i;
    if (l < 16)
        ((float*)((char*)ws + NTILE * 1024))[gt * 16 + l] = bsrc[0] * LOG2E;
}

// one R tile: MFMA -> exp2 -> swizzled RT stores -> rowsum accumulate
#define R_TILE(BF, BV, TT)                                                   \
    do {                                                                     \
        f32x4 acc = {(BV), (BV), (BV), (BV)};                                \
        acc = MFMA16(af.v, (BF).v, acc);                                     \
        const float e0 = EXP2(acc[0]), e1 = EXP2(acc[1]);                    \
        const float e2 = EXP2(acc[2]), e3 = EXP2(acc[3]);                    \
        const int kk = ((TT) << 4) + l15;                                    \
        RT[q * 4 + 0][hb][kk][p] = (__fp16)e0;                               \
        RT[q * 4 + 1][hb][kk][p] = (__fp16)e1;                               \
        RT[q * 4 + 2][hb][kk][p] = (__fp16)e2;                               \
        RT[q * 4 + 3][hb][kk][p] = (__fp16)e3;                               \
        es0 += e0; es1 += e1; es2 += e2; es3 += e3;                          \
    } while (0)

// one J tile (JIT load): MFMA -> exp2 -> JT stores -> rowsum accumulate
#define J_TILE(GT, TT, MP)                                                   \
    do {                                                                     \
        V8 bf; bf.i = *(const i32x4*)(wsb + (size_t)(GT) * 1024 + l * 16);   \
        const float bv = wbias[(GT) * 16 + l15];                             \
        f32x4 acc = {bv, bv, bv, bv};                                        \
        acc = MFMA16(af.v, bf.v, acc);                                       \
        const float e0 = EXP2(acc[0]), e1 = EXP2(acc[1]);                    \
        const float e2 = EXP2(acc[2]), e3 = EXP2(acc[3]);                    \
        const int kk = ((TT) << 4) + l15;                                    \
        JT[q * 4 + 0][kk][(MP)] = (__fp16)e0;                                \
        JT[q * 4 + 1][kk][(MP)] = (__fp16)e1;                                \
        JT[q * 4 + 2][kk][(MP)] = (__fp16)e2;                                \
        JT[q * 4 + 3][kk][(MP)] = (__fp16)e3;                                \
        ej0 += e0; ej1 += e1; ej2 += e2; ej3 += e3;                          \
    } while (0)

// A-frag staging for timestep block ITN (kept live across barriers)
#define AF_LOAD(ITN)                                                         \
    do {                                                                     \
        const float* xa_ = x_a + ((size_t)b * T_ + (ITN) * 16 + l15) * AUX_ + q * 8; \
        const f32x4 x0_ = *(const f32x4*)xa_;                                \
        const f32x4 x1_ = *(const f32x4*)(xa_ + 4);                          \
        af.p[0] = __builtin_amdgcn_cvt_pkrtz(x0_.x, x0_.y);                  \
        af.p[1] = __builtin_amdgcn_cvt_pkrtz(x0_.z, x0_.w);                  \
        af.p[2] = __builtin_amdgcn_cvt_pkrtz(x1_.x, x1_.y);                  \
        af.p[3] = __builtin_amdgcn_cvt_pkrtz(x1_.z, x1_.w);                  \
    } while (0)

// waves 0..13: half of J group a_pr (2 tiles) -> JT + ph[w]
#define J_PAIR()                                                             \
    do {                                                                     \
        float ej0 = 0.f, ej1 = 0.f, ej2 = 0.f, ej3 = 0.f;                    \
        const int mp = a_pr ^ sx;                                            \
        J_TILE((64 + a_pr) * 4 + tb + 0, tb + 0, mp);                        \
        J_TILE((64 + a_pr) * 4 + tb + 1, tb + 1, mp);                        \
        ej0 = sum16_all(ej0); ej1 = sum16_all(ej1);                          \
        ej2 = sum16_all(ej2); ej3 = sum16_all(ej3);                          \
        if (l15 == 0) {                                                      \
            ph[w][q * 4 + 0] = ej0;                                          \
            ph[w][q * 4 + 1] = ej1;                                          \
            ph[w][q * 4 + 2] = ej2;                                          \
            ph[w][q * 4 + 3] = ej3;                                          \
        }                                                                    \
    } while (0)

// wave 14: full J group 7 (4 tiles) -> JT + xj[.][7] directly (no merge)
#define J_FULL(ITN)                                                          \
    do {                                                                     \
        float ej0 = 0.f, ej1 = 0.f, ej2 = 0.f, ej3 = 0.f;                    \
        const int mp = 7 ^ sx;                                               \
        J_TILE(284, 0, mp);                                                  \
        J_TILE(285, 1, mp);                                                  \
        J_TILE(286, 2, mp);                                                  \
        J_TILE(287, 3, mp);                                                  \
        ej0 = sum16_all(ej0); ej1 = sum16_all(ej1);                          \
        ej2 = sum16_all(ej2); ej3 = sum16_all(ej3);                          \
        if (l15 == 0) {                                                      \
            xj[q * 4 + 0][mp] = (__fp16)(xm_lds[(ITN) * 16 + q * 4 + 0][7] * __builtin_amdgcn_rcpf(ej0)); \
            xj[q * 4 + 1][mp] = (__fp16)(xm_lds[(ITN) * 16 + q * 4 + 1][7] * __builtin_amdgcn_rcpf(ej1)); \
            xj[q * 4 + 2][mp] = (__fp16)(xm_lds[(ITN) * 16 + q * 4 + 2][7] * __builtin_amdgcn_rcpf(ej2)); \
            xj[q * 4 + 3][mp] = (__fp16)(xm_lds[(ITN) * 16 + q * 4 + 3][7] * __builtin_amdgcn_rcpf(ej3)); \
        }                                                                    \
    } while (0)

// ---------------- main ----------------
__global__
__attribute__((amdgpu_flat_work_group_size(1024, 1024), amdgpu_waves_per_eu(4, 4)))
void nomc_main(const float* __restrict__ x_m, const float* __restrict__ x_a,
               const float* __restrict__ Wo, const float* __restrict__ bo,
               const float* __restrict__ Wfc, const float* __restrict__ bfc,
               const void* __restrict__ ws, float* __restrict__ out)
{
    const int b = blockIdx.x, tid = threadIdx.x;
    const int w = tid >> 6, l = tid & 63, q = l >> 4, l15 = l & 15;

    __shared__ __align__(16) __fp16 RT[16][8][64][8];   // 131072 B  RT[t][h>>3][k][(h&7)^((t>>2)<<1)]=e
    __shared__ __align__(16) __fp16 JT[16][64][8];      //  16384 B  JT[t][k][m^((t>>2)<<1)]=e_j
    __shared__ float sinv[16][64];                      //   4096 B  1/rowsum(R)
    __shared__ __align__(16) __fp16 xj[16][8];          //    256 B  [t][m^((t>>2)<<1)]=xm/s_j
    __shared__ __align__(16) __fp16 minL[16][64];       //   2048 B  m_in[t][k]
    __shared__ float xm_lds[T_][M_];                    //   8192 B
    __shared__ float cfin_lds[H_];                      //    256 B
    __shared__ float ph[16][16];                        //   1024 B  J half-rowsums [wave][t] (rows 0..13)
    // total 163328 <= 163840

    {   // stage x_m once
        const float* xmb = x_m + (size_t)b * T_ * M_;
        for (int i = tid; i < T_ * M_; i += 1024) (&xm_lds[0][0])[i] = xmb[i];
    }
    __syncthreads();

    const char* wsb = (const char*)ws;
    const float* wbias = (const float*)(wsb + NTILE * 1024);
    const int a_pr = w >> 1;                 // pair J group (waves 0..13)
    const int tb = (w & 1) ? 2 : 0;          // pair J tile base
    const int sx = q << 1;                   // store-side bank swizzle

    V8 af;                                   // A-frag, persists across barriers
    AF_LOAD(0);
    // prologue: J work for it=0 (normally hidden under scan(it-1))
    if (w < 14)       J_PAIR();
    else if (w == 14) J_FULL(0);
    __syncthreads();                         // JT(0), ph(0), xj7(0) visible

    // R rotation preload: group 4w, tiles 0..3 (steady-state across its)
    V8 rc0, rc1, rc2, rc3; float rb0, rb1, rb2, rb3;
    {
        const int gt0 = w * 16;
        rc0.i = *(const i32x4*)(wsb + (size_t)(gt0 + 0) * 1024 + l * 16);
        rc1.i = *(const i32x4*)(wsb + (size_t)(gt0 + 1) * 1024 + l * 16);
        rc2.i = *(const i32x4*)(wsb + (size_t)(gt0 + 2) * 1024 + l * 16);
        rc3.i = *(const i32x4*)(wsb + (size_t)(gt0 + 3) * 1024 + l * 16);
        rb0 = wbias[(gt0 + 0) * 16 + l15];
        rb1 = wbias[(gt0 + 1) * 16 + l15];
        rb2 = wbias[(gt0 + 2) * 16 + l15];
        rb3 = wbias[(gt0 + 3) * 16 + l15];
    }

    float c0 = 0.f, c1 = 0.f, c2 = 0.f, c3 = 0.f;   // c[kt*16 + l15], q-replicated

    for (int it = 0; it < 16; ++it) {
        // ---- pair J-finalize: merge ph halves -> xj (groups 0..6) ----
        if ((w & 1) == 0 && w < 14 && l15 == 0) {
#pragma unroll
            for (int r = 0; r < 4; ++r) {
                const int t = q * 4 + r;
                const float tot = ph[w][t] + ph[w + 1][t];
                xj[t][a_pr ^ sx] =
                    (__fp16)(xm_lds[it * 16 + t][a_pr] * __builtin_amdgcn_rcpf(tot));
            }
        }

        // ---- 4 R groups per wave (uniform), steady-state depth-1 rotation ----
#pragma unroll 1
        for (int g = 0; g < 4; ++g) {
            const int gg = w * 4 + g;                    // 0..63
            const int gtn = (w * 4 + ((g + 1) & 3)) * 4; // next slot (g=3 -> next it's group 0)
            V8 n0, n1, n2, n3; float a0, a1, a2, a3;
            n0.i = *(const i32x4*)(wsb + (size_t)(gtn + 0) * 1024 + l * 16);
            n1.i = *(const i32x4*)(wsb + (size_t)(gtn + 1) * 1024 + l * 16);
            n2.i = *(const i32x4*)(wsb + (size_t)(gtn + 2) * 1024 + l * 16);
            n3.i = *(const i32x4*)(wsb + (size_t)(gtn + 3) * 1024 + l * 16);
            a0 = wbias[(gtn + 0) * 16 + l15];
            a1 = wbias[(gtn + 1) * 16 + l15];
            a2 = wbias[(gtn + 2) * 16 + l15];
            a3 = wbias[(gtn + 3) * 16 + l15];
            const int hb = gg >> 3, p = (gg & 7) ^ sx;   // swizzled slot
            float es0 = 0.f, es1 = 0.f, es2 = 0.f, es3 = 0.f;
            R_TILE(rc0, rb0, 0);
            R_TILE(rc1, rb1, 1);
            R_TILE(rc2, rb2, 2);
            R_TILE(rc3, rb3, 3);
            const float sr0 = sum16_all(es0), sr1 = sum16_all(es1);
            const float sr2 = sum16_all(es2), sr3 = sum16_all(es3);
            if (l15 == 0) {
                sinv[q * 4 + 0][gg] = __builtin_amdgcn_rcpf(sr0);
                sinv[q * 4 + 1][gg] = __builtin_amdgcn_rcpf(sr1);
                sinv[q * 4 + 2][gg] = __builtin_amdgcn_rcpf(sr2);
                sinv[q * 4 + 3][gg] = __builtin_amdgcn_rcpf(sr3);
            }
            rc0 = n0; rc1 = n1; rc2 = n2; rc3 = n3;
            rb0 = a0; rb1 = a1; rb2 = a2; rb3 = a3;
        }
        __syncthreads();   // barrier B: RT/sinv/xj complete

        // ====== m_in pass (parallel, c-independent): minL[t][k] = xj[t].JT[t][k] ======
        // JT and xj carry the SAME (w>>2)-dependent k-permutation inside each
        // 16B chunk, so the dot2 pairs still line up.
        {
            V8 jv; jv.v = *(const f16x8*)&JT[w][l][0];
            V8 xv; xv.v = *(const f16x8*)&xj[w][0];
            float s = 0.f;
            s = dot2(jv.p[0], xv.p[0], s);
            s = dot2(jv.p[1], xv.p[1], s);
            s = dot2(jv.p[2], xv.p[2], s);
            s = dot2(jv.p[3], xv.p[3], s);
            minL[w][l] = (__fp16)s;
        }
        __syncthreads();   // barrier C

        // ============ scan (wave 15) ∥ J phase for it+1 (waves 0..14) ============
        if (w == 15) {
            const int ab = q << 5;              // A0 byte base = lane 8q
            for (int u = 0; u < 16; ++u) {
                const int sig = (u >> 2) & 3;   // matches producer swizzle
                // ---- c-independent prefetch (no fences -> compiler pipelines) ----
                const float mi0 = (float)minL[u][l15];
                const float mi1 = (float)minL[u][16 + l15];
                const float mi2 = (float)minL[u][32 + l15];
                const float mi3 = (float)minL[u][48 + l15];
                const float svl = sinv[u][l];
                V8 b00, b01, b10, b11, b20, b21, b30, b31;
                b00.v = *(const f16x8*)&RT[u][q][l15][0];
                b01.v = *(const f16x8*)&RT[u][4 + q][l15][0];
                b10.v = *(const f16x8*)&RT[u][q][16 + l15][0];
                b11.v = *(const f16x8*)&RT[u][4 + q][16 + l15][0];
                b20.v = *(const f16x8*)&RT[u][q][32 + l15][0];
                b21.v = *(const f16x8*)&RT[u][4 + q][32 + l15][0];
                b30.v = *(const f16x8*)&RT[u][q][48 + l15][0];
                b31.v = *(const f16x8*)&RT[u][4 + q][48 + l15][0];
                // ---- chat_l = c[l] * sinv[u][l]  (in-reg, RNE) ----
                const float cown = (q == 0) ? c0 : (q == 1) ? c1 : (q == 2) ? c2 : c3;
                const int spk = pack_pair_rne(cown * svl);  // lane pair 2P,2P+1 -> chat pair P
                // ---- A-frags via bpermute: A0 pair jp <- lane 8q+2(jp^sig);
                //      A1 pair jp <- lane 32+8q+2(jp^sig) (offset 128 folds) ----
                V8 A0f, A1f;
                A0f.i[0] = __builtin_amdgcn_ds_bpermute(ab + ((0 ^ sig) << 3), spk);
                A0f.i[1] = __builtin_amdgcn_ds_bpermute(ab + ((1 ^ sig) << 3), spk);
                A0f.i[2] = __builtin_amdgcn_ds_bpermute(ab + ((2 ^ sig) << 3), spk);
                A0f.i[3] = __builtin_amdgcn_ds_bpermute(ab + ((3 ^ sig) << 3), spk);
                A1f.i[0] = __builtin_amdgcn_ds_bpermute(128 + ab + ((0 ^ sig) << 3), spk);
                A1f.i[1] = __builtin_amdgcn_ds_bpermute(128 + ab + ((1 ^ sig) << 3), spk);
                A1f.i[2] = __builtin_amdgcn_ds_bpermute(128 + ab + ((2 ^ sig) << 3), spk);
                A1f.i[3] = __builtin_amdgcn_ds_bpermute(128 + ab + ((3 ^ sig) << 3), spk);
                // ---- 2-deep MFMA chains, C-init = m_in ----
                f32x4 a0 = {mi0, mi0, mi0, mi0};
                a0 = MFMA16(A0f.v, b00.v, a0);
                a0 = MFMA16(A1f.v, b01.v, a0);
                f32x4 a1 = {mi1, mi1, mi1, mi1};
                a1 = MFMA16(A0f.v, b10.v, a1);
                a1 = MFMA16(A1f.v, b11.v, a1);
                f32x4 a2 = {mi2, mi2, mi2, mi2};
                a2 = MFMA16(A0f.v, b20.v, a2);
                a2 = MFMA16(A1f.v, b21.v, a2);
                f32x4 a3 = {mi3, mi3, mi3, mi3};
                a3 = MFMA16(A0f.v, b30.v, a3);
                a3 = MFMA16(A1f.v, b31.v, a3);
                c0 = a0[0]; c1 = a1[0]; c2 = a2[0]; c3 = a3[0];
            }
            if (it < 15) AF_LOAD(it + 1);
        } else if (it < 15) {
            AF_LOAD(it + 1);                 // A-frag for next block (used by J now, R later)
            if (w < 14) J_PAIR();            // JT(it+1) + ph(it+1)
            else        J_FULL(it + 1);      // JT(it+1) + xj[.][7](it+1)
        }
        __syncthreads();   // barrier D
    }

    // ---- epilogue: out = (sigmoid(xa_T@Wo+bo) * c_T) @ Wfc + bfc ----
    if (w == 15) {
        const float cown = (q == 0) ? c0 : (q == 1) ? c1 : (q == 2) ? c2 : c3;
        cfin_lds[l] = cown;                              // all-lane write
        LDS_FENCE();
        const float* xa = x_a + ((size_t)b * T_ + (T_ - 1)) * AUX_;
        float L = bo[l];
#pragma unroll
        for (int a = 0; a < AUX_; ++a) L = fmaf(xa[a], Wo[a * H_ + l], L);
        const float o = 1.0f / (1.0f + __expf(-L));
        const float cfin = cfin_lds[l];
        float p = (o * cfin) * Wfc[l];
        p = sum64_uni(p);
        if (l == 0) out[b] = p + bfc[0];
        out[B_ + b * H_ + l] = cfin;                     // c_final, coalesced
    }
}

} // namespace

extern "C" void kernel_launch(void* const* d_in, const int* in_sizes, int n_in,
                              void* d_out, int out_size, void* d_ws, size_t ws_size,
                              hipStream_t stream) {
    const float* x_m = (const float*)d_in[0];
    const float* x_a = (const float*)d_in[1];
    const float* Wj  = (const float*)d_in[2];
    const float* bj  = (const float*)d_in[3];
    const float* Wr  = (const float*)d_in[4];
    const float* br  = (const float*)d_in[5];
    const float* Wo  = (const float*)d_in[6];
    const float* bo  = (const float*)d_in[7];
    const float* Wfc = (const float*)d_in[8];
    const float* bfc = (const float*)d_in[9];
    float* out = (float*)d_out;

    hipLaunchKernelGGL(nomc_prep, dim3(NTILE), dim3(64), 0, stream,
                       Wj, bj, Wr, br, d_ws);
    hipLaunchKernelGGL(nomc_main, dim3(B_), dim3(1024), 0, stream,
                       x_m, x_a, Wo, bo, Wfc, bfc, d_ws, out);
}

// Round 12
// 214.245 us; speedup vs baseline: 1.1898x; 1.0947x over previous
//
#include <hip/hip_runtime.h>

// NoMCOutModel round 26: RESUBMIT of r25 (bench infra failed twice; kernel
// never ran). Lean r21 base + J-under-scan (no rotation) + 2-barrier it.
// r24 post-mortem: rotation+J-hide+spill = -2us net; the rotation regs
// (rc/rb, 48 VGPR) live across barriers pushed past the allocator's HARD
// 64-VGPR ceiling (waves_per_eu(4,4) did NOT lift it: VGPR stayed 64 in
// r23/r24) -> scratch (WRITE 16MB). Lesson: every structure must fit 64.
// Unconfounded design: r21's JIT-load R phase (proven 172.8, 56 VGPR)
// + J hidden under the scan with a SIMPLER mapping: waves 0..7 each own a
// full J group (4 tiles, full rowsum, write xj directly -- no ph, no
// merge). m_in moves to it-top (JT/xj(it) are visible since barrier D of
// the previous window); minL rides barrier B to the scan -> barrier C
// DELETED: 2 barriers/it. Overlap region: w15 scans(it); waves 0..7
// produce JT/xj(it+1); all stage af(it+1) (+8 VGPR across D, the only
// pressure add). Race audit: JT/xj(it) consumed pre-B, rewritten post-B;
// minL/RT/sinv written pre-B, read post-B, rewritten after D. Numeric
// delta: J rowsum single-accumulate vs half-merge (~1ulp on sinv_j).
// Scan/prep/epilogue: identical to r18 lineage.

namespace {

constexpr int B_ = 256, T_ = 256, M_ = 8, AUX_ = 32, H_ = 64;
constexpr int NTILE = 288;               // (64*64 + 8*64)/16 logit col-tiles
constexpr float LOG2E = 1.4426950408889634f;

typedef __fp16 f16x2 __attribute__((ext_vector_type(2)));
typedef __fp16 f16x8 __attribute__((ext_vector_type(8)));
typedef float  f32x4 __attribute__((ext_vector_type(4)));
typedef int    i32x4 __attribute__((ext_vector_type(4)));

union V8 { f16x8 v; f16x2 p[4]; i32x4 i; };

#if __has_builtin(__builtin_amdgcn_exp2f)
#define EXP2(x) __builtin_amdgcn_exp2f(x)
#else
#define EXP2(x) exp2f(x)
#endif

#define MFMA16(A, Bv, C) __builtin_amdgcn_mfma_f32_16x16x32_f16((A), (Bv), (C), 0, 0, 0)

__device__ __forceinline__ float dot2(f16x2 a, f16x2 b, float c) {
    return __builtin_amdgcn_fdot2(a, b, c, false);
}

template <int CTRL>
__device__ __forceinline__ float dpp_add(float v) {
    int t = __builtin_amdgcn_update_dpp(0, __builtin_bit_cast(int, v),
                                        CTRL, 0xf, 0xf, true);
    return v + __builtin_bit_cast(float, t);
}
__device__ __forceinline__ float sum16_all(float v) {
    v = dpp_add<0xB1>(v);   // quad_perm [1,0,3,2]
    v = dpp_add<0x4E>(v);   // quad_perm [2,3,0,1]
    v = dpp_add<0x141>(v);  // row_half_mirror
    v = dpp_add<0x140>(v);  // row_mirror
    return v;
}
__device__ __forceinline__ float sum64_uni(float v) {
    v = dpp_add<0x111>(v); v = dpp_add<0x112>(v); v = dpp_add<0x114>(v);
    v = dpp_add<0x118>(v); v = dpp_add<0x142>(v); v = dpp_add<0x143>(v);
    return __builtin_bit_cast(float,
        __builtin_amdgcn_readlane(__builtin_bit_cast(int, v), 63));
}

// RNE pair-pack: every lane ends with (f16(chat[2P]), f16(chat[2P+1])) where
// P = lane>>1. Own value is converted RNE ((__fp16) cast = v_cvt_f16_f32),
// then quad_perm DPP broadcasts the even/odd pair members to both lanes.
__device__ __forceinline__ int pack_pair_rne(float v) {
    const int hv = (int)__builtin_bit_cast(unsigned short, (__fp16)v);
    const int ev = __builtin_amdgcn_update_dpp(0, hv, 0xA0, 0xf, 0xf, true); // [0,0,2,2]
    const int ov = __builtin_amdgcn_update_dpp(0, hv, 0xF5, 0xf, 0xf, true); // [1,1,3,3]
    return ev | (ov << 16);
}

#define LDS_FENCE() __asm__ volatile("s_waitcnt lgkmcnt(0)" ::: "memory")

// ---------------- prep: W -> f16 MFMA B-frag layout in ws ----------------
// ws[gt*1024 + lane*16] : f16x8 frag, B[k = (lane>>4)*8 + j][n = gt*16+(lane&15)]
// ws + 288*1024 : float bias[4608] (log2e-scaled)
__global__ __launch_bounds__(64)
void nomc_prep(const float* __restrict__ Wj, const float* __restrict__ bj,
               const float* __restrict__ Wr, const float* __restrict__ br,
               void* __restrict__ ws)
{
    const int gt = blockIdx.x;           // 0..287
    const int l = threadIdx.x, q = l >> 4, l15 = l & 15;
    const float* src; const float* bsrc; int stride;
    if (gt < 256) { const int n = gt * 16 + l15;        src = Wr + n; bsrc = br + n; stride = 4096; }
    else          { const int n = (gt - 256) * 16 + l15; src = Wj + n; bsrc = bj + n; stride = 512; }
    V8 v;
#pragma unroll
    for (int j = 0; j < 4; ++j) {
        const float f0 = src[(q * 8 + 2 * j)     * stride] * LOG2E;
        const float f1 = src[(q * 8 + 2 * j + 1) * stride] * LOG2E;
        v.p[j] = __builtin_amdgcn_cvt_pkrtz(f0, f1);
    }
    *(i32x4*)((char*)ws + (size_t)gt * 1024 + l * 16) = v.i;
    if (l < 16)
        ((float*)((char*)ws + NTILE * 1024))[gt * 16 + l] = bsrc[0] * LOG2E;
}

// A-frag staging for timestep block ITN
#define AF_LOAD(ITN)                                                         \
    do {                                                                     \
        const float* xa_ = x_a + ((size_t)b * T_ + (ITN) * 16 + l15) * AUX_ + q * 8; \
        const f32x4 x0_ = *(const f32x4*)xa_;                                \
        const f32x4 x1_ = *(const f32x4*)(xa_ + 4);                          \
        af.p[0] = __builtin_amdgcn_cvt_pkrtz(x0_.x, x0_.y);                  \
        af.p[1] = __builtin_amdgcn_cvt_pkrtz(x0_.z, x0_.w);                  \
        af.p[2] = __builtin_amdgcn_cvt_pkrtz(x1_.x, x1_.y);                  \
        af.p[3] = __builtin_amdgcn_cvt_pkrtz(x1_.z, x1_.w);                  \
    } while (0)

// waves 0..7: full J group w (4 tiles, JIT loads) -> JT + xj[.][w] direct
#define J_GROUP(ITN)                                                         \
    do {                                                                     \
        float ej0 = 0.f, ej1 = 0.f, ej2 = 0.f, ej3 = 0.f;                    \
        const int mp = w ^ sx;                                               \
        _Pragma("unroll")                                                    \
        for (int tt = 0; tt < 4; ++tt) {                                     \
            const int gt = (64 + w) * 4 + tt;                                \
            V8 bf; bf.i = *(const i32x4*)(wsb + (size_t)gt * 1024 + l * 16); \
            const float bv = wbias[gt * 16 + l15];                           \
            f32x4 acc = {bv, bv, bv, bv};                                    \
            acc = MFMA16(af.v, bf.v, acc);                                   \
            const float e0 = EXP2(acc[0]), e1 = EXP2(acc[1]);                \
            const float e2 = EXP2(acc[2]), e3 = EXP2(acc[3]);                \
            const int kk = (tt << 4) + l15;                                  \
            JT[q * 4 + 0][kk][mp] = (__fp16)e0;                              \
            JT[q * 4 + 1][kk][mp] = (__fp16)e1;                              \
            JT[q * 4 + 2][kk][mp] = (__fp16)e2;                              \
            JT[q * 4 + 3][kk][mp] = (__fp16)e3;                              \
            ej0 += e0; ej1 += e1; ej2 += e2; ej3 += e3;                      \
        }                                                                    \
        ej0 = sum16_all(ej0); ej1 = sum16_all(ej1);                          \
        ej2 = sum16_all(ej2); ej3 = sum16_all(ej3);                          \
        if (l15 == 0) {                                                      \
            xj[q * 4 + 0][mp] = (__fp16)(xm_lds[(ITN) * 16 + q * 4 + 0][w] * __builtin_amdgcn_rcpf(ej0)); \
            xj[q * 4 + 1][mp] = (__fp16)(xm_lds[(ITN) * 16 + q * 4 + 1][w] * __builtin_amdgcn_rcpf(ej1)); \
            xj[q * 4 + 2][mp] = (__fp16)(xm_lds[(ITN) * 16 + q * 4 + 2][w] * __builtin_amdgcn_rcpf(ej2)); \
            xj[q * 4 + 3][mp] = (__fp16)(xm_lds[(ITN) * 16 + q * 4 + 3][w] * __builtin_amdgcn_rcpf(ej3)); \
        }                                                                    \
    } while (0)

// ---------------- main ----------------
__global__ __launch_bounds__(1024, 4)
void nomc_main(const float* __restrict__ x_m, const float* __restrict__ x_a,
               const float* __restrict__ Wo, const float* __restrict__ bo,
               const float* __restrict__ Wfc, const float* __restrict__ bfc,
               const void* __restrict__ ws, float* __restrict__ out)
{
    const int b = blockIdx.x, tid = threadIdx.x;
    const int w = tid >> 6, l = tid & 63, q = l >> 4, l15 = l & 15;

    __shared__ __align__(16) __fp16 RT[16][8][64][8];   // 131072 B  RT[t][h>>3][k][(h&7)^((t>>2)<<1)]=e
    __shared__ __align__(16) __fp16 JT[16][64][8];      //  16384 B  JT[t][k][m^((t>>2)<<1)]=e_j
    __shared__ float sinv[16][64];                      //   4096 B  1/rowsum(R)
    __shared__ __align__(16) __fp16 xj[16][8];          //    256 B  [t][m^((t>>2)<<1)]=xm/s_j
    __shared__ __align__(16) __fp16 minL[16][64];       //   2048 B  m_in[t][k]
    __shared__ float xm_lds[T_][M_];                    //   8192 B
    __shared__ float cfin_lds[H_];                      //    256 B
    // total 162304 <= 163840

    {   // stage x_m once
        const float* xmb = x_m + (size_t)b * T_ * M_;
        for (int i = tid; i < T_ * M_; i += 1024) (&xm_lds[0][0])[i] = xmb[i];
    }
    __syncthreads();

    const char* wsb = (const char*)ws;
    const float* wbias = (const float*)(wsb + NTILE * 1024);
    const int sx = q << 1;                   // store-side bank swizzle

    V8 af;                                   // A-frag, persists across barriers
    AF_LOAD(0);
    if (w < 8) J_GROUP(0);                   // prologue J(0)
    __syncthreads();                         // JT(0), xj(0) visible

    float c0 = 0.f, c1 = 0.f, c2 = 0.f, c3 = 0.f;   // c[kt*16 + l15], q-replicated

    for (int it = 0; it < 16; ++it) {
        // ====== m_in(it) at it-top: minL[t][k] = xj[t].JT[t][k] ======
        // JT/xj(it) were written during the previous overlap window
        // (visible since barrier D). minL rides barrier B to the scan.
        {
            V8 jv; jv.v = *(const f16x8*)&JT[w][l][0];
            V8 xv; xv.v = *(const f16x8*)&xj[w][0];
            float s = 0.f;
            s = dot2(jv.p[0], xv.p[0], s);
            s = dot2(jv.p[1], xv.p[1], s);
            s = dot2(jv.p[2], xv.p[2], s);
            s = dot2(jv.p[3], xv.p[3], s);
            minL[w][l] = (__fp16)s;
        }

        // ---- 4 R groups per wave, JIT loads (r21's proven codegen) ----
#pragma unroll 1
        for (int g = 0; g < 4; ++g) {
            const int gg = w * 4 + g;                    // 0..63
            float es0 = 0.f, es1 = 0.f, es2 = 0.f, es3 = 0.f;
            const int hb = gg >> 3, p = (gg & 7) ^ sx;   // swizzled slot
#pragma unroll
            for (int tt = 0; tt < 4; ++tt) {
                const int gt = gg * 4 + tt;
                V8 bf; bf.i = *(const i32x4*)(wsb + (size_t)gt * 1024 + l * 16);
                const float bv = wbias[gt * 16 + l15];
                f32x4 acc = {bv, bv, bv, bv};
                acc = MFMA16(af.v, bf.v, acc);
                const float e0 = EXP2(acc[0]), e1 = EXP2(acc[1]);
                const float e2 = EXP2(acc[2]), e3 = EXP2(acc[3]);
                const int kk = (tt << 4) + l15;
                RT[q * 4 + 0][hb][kk][p] = (__fp16)e0;
                RT[q * 4 + 1][hb][kk][p] = (__fp16)e1;
                RT[q * 4 + 2][hb][kk][p] = (__fp16)e2;
                RT[q * 4 + 3][hb][kk][p] = (__fp16)e3;
                es0 += e0; es1 += e1; es2 += e2; es3 += e3;
            }
            const float sr0 = sum16_all(es0), sr1 = sum16_all(es1);
            const float sr2 = sum16_all(es2), sr3 = sum16_all(es3);
            if (l15 == 0) {
                sinv[q * 4 + 0][gg] = __builtin_amdgcn_rcpf(sr0);
                sinv[q * 4 + 1][gg] = __builtin_amdgcn_rcpf(sr1);
                sinv[q * 4 + 2][gg] = __builtin_amdgcn_rcpf(sr2);
                sinv[q * 4 + 3][gg] = __builtin_amdgcn_rcpf(sr3);
            }
        }
        __syncthreads();   // barrier B: RT, sinv, minL visible

        // ============ scan(it) (wave 15) ∥ J(it+1) (waves 0..7) ============
        if (w == 15) {
            const int ab = q << 5;              // A0 byte base = lane 8q
            for (int u = 0; u < 16; ++u) {
                const int sig = (u >> 2) & 3;   // matches producer swizzle
                // ---- c-independent prefetch (no fences -> compiler pipelines) ----
                const float mi0 = (float)minL[u][l15];
                const float mi1 = (float)minL[u][16 + l15];
                const float mi2 = (float)minL[u][32 + l15];
                const float mi3 = (float)minL[u][48 + l15];
                const float svl = sinv[u][l];
                V8 b00, b01, b10, b11, b20, b21, b30, b31;
                b00.v = *(const f16x8*)&RT[u][q][l15][0];
                b01.v = *(const f16x8*)&RT[u][4 + q][l15][0];
                b10.v = *(const f16x8*)&RT[u][q][16 + l15][0];
                b11.v = *(const f16x8*)&RT[u][4 + q][16 + l15][0];
                b20.v = *(const f16x8*)&RT[u][q][32 + l15][0];
                b21.v = *(const f16x8*)&RT[u][4 + q][32 + l15][0];
                b30.v = *(const f16x8*)&RT[u][q][48 + l15][0];
                b31.v = *(const f16x8*)&RT[u][4 + q][48 + l15][0];
                // ---- chat_l = c[l] * sinv[u][l]  (in-reg, RNE) ----
                const float cown = (q == 0) ? c0 : (q == 1) ? c1 : (q == 2) ? c2 : c3;
                const int spk = pack_pair_rne(cown * svl);  // lane pair 2P,2P+1 -> chat pair P
                // ---- A-frags via bpermute: A0 pair jp <- lane 8q+2(jp^sig);
                //      A1 pair jp <- lane 32+8q+2(jp^sig) (offset 128 folds) ----
                V8 A0f, A1f;
                A0f.i[0] = __builtin_amdgcn_ds_bpermute(ab + ((0 ^ sig) << 3), spk);
                A0f.i[1] = __builtin_amdgcn_ds_bpermute(ab + ((1 ^ sig) << 3), spk);
                A0f.i[2] = __builtin_amdgcn_ds_bpermute(ab + ((2 ^ sig) << 3), spk);
                A0f.i[3] = __builtin_amdgcn_ds_bpermute(ab + ((3 ^ sig) << 3), spk);
                A1f.i[0] = __builtin_amdgcn_ds_bpermute(128 + ab + ((0 ^ sig) << 3), spk);
                A1f.i[1] = __builtin_amdgcn_ds_bpermute(128 + ab + ((1 ^ sig) << 3), spk);
                A1f.i[2] = __builtin_amdgcn_ds_bpermute(128 + ab + ((2 ^ sig) << 3), spk);
                A1f.i[3] = __builtin_amdgcn_ds_bpermute(128 + ab + ((3 ^ sig) << 3), spk);
                // ---- 2-deep MFMA chains, C-init = m_in ----
                f32x4 a0 = {mi0, mi0, mi0, mi0};
                a0 = MFMA16(A0f.v, b00.v, a0);
                a0 = MFMA16(A1f.v, b01.v, a0);
                f32x4 a1 = {mi1, mi1, mi1, mi1};
                a1 = MFMA16(A0f.v, b10.v, a1);
                a1 = MFMA16(A1f.v, b11.v, a1);
                f32x4 a2 = {mi2, mi2, mi2, mi2};
                a2 = MFMA16(A0f.v, b20.v, a2);
                a2 = MFMA16(A1f.v, b21.v, a2);
                f32x4 a3 = {mi3, mi3, mi3, mi3};
                a3 = MFMA16(A0f.v, b30.v, a3);
                a3 = MFMA16(A1f.v, b31.v, a3);
                c0 = a0[0]; c1 = a1[0]; c2 = a2[0]; c3 = a3[0];
            }
            if (it < 15) AF_LOAD(it + 1);
        } else if (it < 15) {
            AF_LOAD(it + 1);                 // af(it+1) for J now, R next it
            if (w < 8) J_GROUP(it + 1);      // JT(it+1) + xj(it+1), hidden
        }
        __syncthreads();   // barrier D
    }

    // ---- epilogue: out = (sigmoid(xa_T@Wo+bo) * c_T) @ Wfc + bfc ----
    if (w == 15) {
        const float cown = (q == 0) ? c0 : (q == 1) ? c1 : (q == 2) ? c2 : c3;
        cfin_lds[l] = cown;                              // all-lane write
        LDS_FENCE();
        const float* xa = x_a + ((size_t)b * T_ + (T_ - 1)) * AUX_;
        float L = bo[l];
#pragma unroll
        for (int a = 0; a < AUX_; ++a) L = fmaf(xa[a], Wo[a * H_ + l], L);
        const float o = 1.0f / (1.0f + __expf(-L));
        const float cfin = cfin_lds[l];
        float p = (o * cfin) * Wfc[l];
        p = sum64_uni(p);
        if (l == 0) out[b] = p + bfc[0];
        out[B_ + b * H_ + l] = cfin;                     // c_final, coalesced
    }
}

} // namespace

extern "C" void kernel_launch(void* const* d_in, const int* in_sizes, int n_in,
                              void* d_out, int out_size, void* d_ws, size_t ws_size,
                              hipStream_t stream) {
    const float* x_m = (const float*)d_in[0];
    const float* x_a = (const float*)d_in[1];
    const float* Wj  = (const float*)d_in[2];
    const float* bj  = (const float*)d_in[3];
    const float* Wr  = (const float*)d_in[4];
    const float* br  = (const float*)d_in[5];
    const float* Wo  = (const float*)d_in[6];
    const float* bo  = (const float*)d_in[7];
    const float* Wfc = (const float*)d_in[8];
    const float* bfc = (const float*)d_in[9];
    float* out = (float*)d_out;

    hipLaunchKernelGGL(nomc_prep, dim3(NTILE), dim3(64), 0, stream,
                       Wj, bj, Wr, br, d_ws);
    hipLaunchKernelGGL(nomc_main, dim3(B_), dim3(1024), 0, stream,
                       x_m, x_a, Wo, bo, Wfc, bfc, d_ws, out);
}